// Round 12
// baseline (392.801 us; speedup 1.0000x reference)
//
#include <hip/hip_runtime.h>
#include <hip/hip_bf16.h>

#define B_ 4096
#define T_ 128
#define F_ 64
#define H_ 32
#define G_ 128  // 4*H

using short8 = __attribute__((ext_vector_type(8))) short;
using f32x4  = __attribute__((ext_vector_type(4))) float;
using uint2v = __attribute__((ext_vector_type(2))) unsigned int;
using uint4v = __attribute__((ext_vector_type(4))) unsigned int;

#define MFMA16(Af, Bf, Cf) __builtin_amdgcn_mfma_f32_16x16x32_bf16((Af), (Bf), (Cf), 0, 0, 0)

__device__ __forceinline__ float sigmoid_f(float z) {
    return __builtin_amdgcn_rcpf(1.0f + __expf(-z));
}
__device__ __forceinline__ unsigned short bfb(float f) {
    return __builtin_bit_cast(unsigned short, __float2bfloat16(f));
}
__device__ __forceinline__ unsigned int pk(float a, float b) {
    return (unsigned int)bfb(a) | ((unsigned int)bfb(b) << 16);
}

// ROUND-7 STRUCTURE (2-wave gate split, transposed recurrence, p-map validated r6-r8),
// SOFTWARE-PIPELINED: the exchange window (barrier -> hfrag assemble) is filled with
// h-independent work so the ds_read round-trip is hidden (R4's stall-hiding property).
//   Encoder iter t:  Ue-MFMA(acc preloaded with bias+x_t proj) -> gates -> write own ->
//     barrier -> [issue ds_read other | cvt x_{t+1} | load x_{t+2} | 8 We-MFMAs -> acc]
//     -> assemble hfrag (lgkm wait lands here).
//   Decoder iter t:  Ud-MFMA -> gates -> write own -> barrier ->
//     [issue ds_read | out-proj of h_{t-1} (2 MFMA + 8 stores)] -> assemble hfrag.
//     Final out-proj in epilogue.
// Arithmetic bit-identical to round 7 (same MFMA C-chain order We0->We1->Ue, same gates,
// same exchange layout) -> absmax must be exactly 1.2207e-4.
extern "C" __global__ __launch_bounds__(128, 1)
void lstm_ae(const float* __restrict__ x,
             const float* __restrict__ We,
             const float* __restrict__ Ue,
             const float* __restrict__ be,
             const float* __restrict__ Wd,
             const float* __restrict__ Ud,
             const float* __restrict__ bd,
             const float* __restrict__ Wout,
             const float* __restrict__ bout,
             float* __restrict__ out)
{
    const int lane = threadIdx.x & 63;
    const int rw   = threadIdx.x >> 6;   // wave 0,1
    const int g    = lane >> 4;
    const int c    = lane & 15;
    const int b0   = blockIdx.x << 4;

    // h exchange: [buf][c*18 + 8*wave + 2*g], stride 18 dwords (r7 layout, 2-way banks)
    __shared__ __align__(16) unsigned int hx[2][16 * 18];

    // ---------------- encoder weights: this wave's 4 gate tiles n = 2q+rw ----------------
    short8 weF[4][2];   // We^T: K=64 -> 2 chunks, natural k-map 8g+i
    short8 ueF[4];      // Ue^T: K=32, p-map p(g,i) = 4g+(i&3)+16*(i>>2)
    f32x4  beC[4];
#pragma unroll
    for (int q = 0; q < 4; ++q) {
        const int n = 2 * q + rw;
#pragma unroll
        for (int kc = 0; kc < 2; ++kc)
#pragma unroll
            for (int i = 0; i < 8; ++i)
                weF[q][kc][i] = (short)bfb(We[(kc * 32 + 8 * g + i) * G_ + 16 * n + c]);
#pragma unroll
        for (int i = 0; i < 8; ++i)
            ueF[q][i] = (short)bfb(Ue[(4 * g + (i & 3) + 16 * (i >> 2)) * G_ + 16 * n + c]);
        beC[q] = *(const f32x4*)(be + 16 * n + 4 * g);
    }

    const float* xr = x + (size_t)(b0 + c) * (T_ * F_);
    const int xo = 8 * g;

    short8 hfrag = (short8)0;
    float  cs[4] = {0.f, 0.f, 0.f, 0.f};

#define CVTX(xf0, xf1)                                   \
    {                                                    \
        _Pragma("unroll")                                \
        for (int i = 0; i < 4; ++i) {                    \
            xf0[i]     = (short)bfb(xa[i]);              \
            xf0[4 + i] = (short)bfb(xb[i]);              \
            xf1[i]     = (short)bfb(xc[i]);              \
            xf1[4 + i] = (short)bfb(xd[i]);              \
        }                                                \
    }

#define GATES4(ACC, OWN)                                 \
    {                                                    \
        float hv[4];                                     \
        _Pragma("unroll")                                \
        for (int r = 0; r < 4; ++r) {                    \
            float iv = sigmoid_f(ACC[0][r]);             \
            float fv = sigmoid_f(ACC[1][r]);             \
            float gv = fmaxf(ACC[2][r], 0.f);            \
            float ov = sigmoid_f(ACC[3][r]);             \
            float cc = fmaf(fv, cs[r], iv * gv);         \
            cs[r] = cc;                                  \
            hv[r] = ov * fmaxf(cc, 0.f);                 \
        }                                                \
        OWN.x = pk(hv[0], hv[1]);                        \
        OWN.y = pk(hv[2], hv[3]);                        \
    }

    // ---------------- encoder prologue: acc = bias + x_0 @ We; stage x_1 ----------------
    f32x4 xa = *(const f32x4*)(xr + xo);
    f32x4 xb = *(const f32x4*)(xr + xo + 4);
    f32x4 xc = *(const f32x4*)(xr + 32 + xo);
    f32x4 xd = *(const f32x4*)(xr + 36 + xo);
    short8 xf0, xf1;
    CVTX(xf0, xf1)
    {
        const float* xn = xr + F_;
        xa = *(const f32x4*)(xn + xo);
        xb = *(const f32x4*)(xn + xo + 4);
        xc = *(const f32x4*)(xn + 32 + xo);
        xd = *(const f32x4*)(xn + 36 + xo);
    }
    f32x4 acc[4];
#pragma unroll
    for (int q = 0; q < 4; ++q) {
        acc[q] = MFMA16(weF[q][0], xf0, beC[q]);
        acc[q] = MFMA16(weF[q][1], xf1, acc[q]);
    }

    // =============================== encoder scan ===============================
#pragma unroll 1
    for (int t = 0; t < T_; ++t) {
        // serial region: 4 dependent MFMAs -> gates -> pack -> write
#pragma unroll
        for (int q = 0; q < 4; ++q)
            acc[q] = MFMA16(ueF[q], hfrag, acc[q]);   // z = (bias + x@We) + Ue^T h
        uint2v own;
        GATES4(acc, own)
        *(uint2v*)&hx[t & 1][c * 18 + 8 * rw + 2 * g] = own;
        __syncthreads();

        // exchange window: issue read, then fill with h-independent work
        uint2v oth = *(const uint2v*)&hx[t & 1][c * 18 + 8 * (1 - rw) + 2 * g];
        if (t + 1 < T_) {
            CVTX(xf0, xf1)                              // x_{t+1} (regs loaded at t-1)
            if (t + 2 < T_) {
                const float* xn = xr + (t + 2) * F_;
                xa = *(const f32x4*)(xn + xo);
                xb = *(const f32x4*)(xn + xo + 4);
                xc = *(const f32x4*)(xn + 32 + xo);
                xd = *(const f32x4*)(xn + 36 + xo);
            }
#pragma unroll
            for (int q = 0; q < 4; ++q) {               // next step's x-projection
                acc[q] = MFMA16(weF[q][0], xf0, beC[q]);
                acc[q] = MFMA16(weF[q][1], xf1, acc[q]);
            }
        }
        // assemble (lgkm wait lands here, after the filler)
        uint4v hb;
        hb.x = rw ? oth.x : own.x;   // elems 0-3: hidden 4g+r (wave-0 half)
        hb.y = rw ? oth.y : own.y;
        hb.z = rw ? own.x : oth.x;   // elems 4-7: hidden 16+4g+r (wave-1 half)
        hb.w = rw ? own.y : oth.y;
        hfrag = __builtin_bit_cast(short8, hb);
    }

    // ============ decoder weights + constant input zd = bd + Wd^T hT ============
    short8 udF[4], woF[2];
    f32x4  zd[4], boC[2];
    {
        short8 wdF[4];
#pragma unroll
        for (int q = 0; q < 4; ++q) {
            const int n = 2 * q + rw;
#pragma unroll
            for (int i = 0; i < 8; ++i) {
                const int pr = 4 * g + (i & 3) + 16 * (i >> 2);
                wdF[q][i] = (short)bfb(Wd[pr * G_ + 16 * n + c]);
                udF[q][i] = (short)bfb(Ud[pr * G_ + 16 * n + c]);
            }
        }
#pragma unroll
        for (int q = 0; q < 4; ++q) {
            f32x4 tb = *(const f32x4*)(bd + 16 * (2 * q + rw) + 4 * g);
            zd[q] = MFMA16(wdF[q], hfrag, tb);   // hfrag == full hT here
        }
#pragma unroll
        for (int mi = 0; mi < 2; ++mi) {
            const int m = 2 * rw + mi;
#pragma unroll
            for (int i = 0; i < 8; ++i)
                woF[mi][i] = (short)bfb(Wout[(4 * g + (i & 3) + 16 * (i >> 2)) * F_ + 16 * m + c]);
            float v = bout[16 * m + c];
            boC[mi][0] = v; boC[mi][1] = v; boC[mi][2] = v; boC[mi][3] = v;
        }
    }

    hfrag = (short8)0;
#pragma unroll
    for (int r = 0; r < 4; ++r) cs[r] = 0.f;

    float* ob[4];
#pragma unroll
    for (int r = 0; r < 4; ++r)
        ob[r] = out + (size_t)(b0 + 4 * g + r) * (T_ * F_) + c;

    // ============ decoder scan; out-proj pipelined one step into the window ============
#pragma unroll 1
    for (int t = 0; t < T_; ++t) {
#pragma unroll
        for (int q = 0; q < 4; ++q)
            acc[q] = MFMA16(udF[q], hfrag, zd[q]);   // z = zd + Ud^T h
        uint2v own;
        GATES4(acc, own)
        *(uint2v*)&hx[t & 1][c * 18 + 8 * rw + 2 * g] = own;
        __syncthreads();

        uint2v oth = *(const uint2v*)&hx[t & 1][c * 18 + 8 * (1 - rw) + 2 * g];
        if (t > 0) {
            // out-proj of h_{t-1} (current hfrag, assembled last iter) — window filler
#pragma unroll
            for (int mi = 0; mi < 2; ++mi) {
                f32x4 oac = MFMA16(hfrag, woF[mi], boC[mi]);
                const int m = 2 * rw + mi;
#pragma unroll
                for (int r = 0; r < 4; ++r)
                    ob[r][(t - 1) * F_ + 16 * m] = oac[r];
            }
        }
        uint4v hb;
        hb.x = rw ? oth.x : own.x;
        hb.y = rw ? oth.y : own.y;
        hb.z = rw ? own.x : oth.x;
        hb.w = rw ? own.y : oth.y;
        hfrag = __builtin_bit_cast(short8, hb);      // full h_t
    }
    // epilogue: out-proj of final h
#pragma unroll
    for (int mi = 0; mi < 2; ++mi) {
        f32x4 oac = MFMA16(hfrag, woF[mi], boC[mi]);
        const int m = 2 * rw + mi;
#pragma unroll
        for (int r = 0; r < 4; ++r)
            ob[r][(T_ - 1) * F_ + 16 * m] = oac[r];
    }
}

extern "C" void kernel_launch(void* const* d_in, const int* in_sizes, int n_in,
                              void* d_out, int out_size, void* d_ws, size_t ws_size,
                              hipStream_t stream) {
    (void)in_sizes; (void)n_in; (void)d_ws; (void)ws_size; (void)out_size;
    const float* x    = (const float*)d_in[0];
    const float* We   = (const float*)d_in[1];
    const float* Ue   = (const float*)d_in[2];
    const float* be   = (const float*)d_in[3];
    const float* Wd   = (const float*)d_in[4];
    const float* Ud   = (const float*)d_in[5];
    const float* bd   = (const float*)d_in[6];
    const float* Wout = (const float*)d_in[7];
    const float* bout = (const float*)d_in[8];
    float* out = (float*)d_out;

    dim3 grid(B_ / 16), block(128);
    hipLaunchKernelGGL(lstm_ae, grid, block, 0, stream,
                       x, We, Ue, be, Wd, Ud, bd, Wout, bout, out);
}